// Round 2
// baseline (667.612 us; speedup 1.0000x reference)
//
#include <hip/hip_runtime.h>
#include <hip/hip_bf16.h>

#define NN    500000
#define DIN   256
#define DATT  128
#define NG    4096
#define MT    64          // nodes per block tile

// Fused: h = tanh(x@W1+b1); attn = h@W2+b2; out[batch[n]] += attn[n]*x[n]
// Block: 256 threads (4 waves). x-tile [64][256] fp32 staged once in LDS and
// reused for BOTH the GEMM input and the weighted pooling (x read once from HBM).
// Thread (tc=tid&31, tr=tid>>5) computes 8 nodes x 4 cols of h.
// batch is sorted (int32!) -> per-tile register accumulation, atomics only at
// graph boundaries (~1.5 flushes/tile -> ~3M atomics total vs 128M naive).
__global__ __launch_bounds__(256, 2)
void attnpool_kernel(const float* __restrict__ x,
                     const int* __restrict__ batch,
                     const float* __restrict__ W1,
                     const float* __restrict__ b1,
                     const float* __restrict__ W2,
                     const float* __restrict__ b2,
                     float* __restrict__ out)
{
    __shared__ float xs[MT][DIN];     // 64 KB
    __shared__ float attn_s[MT];
    __shared__ int   bid_s[MT];

    const int tid = threadIdx.x;
    const long long n0 = (long long)blockIdx.x * MT;

    // ---- stage x tile (float4, coalesced). 4096 float4 / 256 threads = 16 each
    const float4* xg = (const float4*)x;
    float4* xsv = (float4*)&xs[0][0];
    #pragma unroll
    for (int i = 0; i < 16; ++i) {
        int j = tid + i * 256;        // float4 index in tile, 0..4095
        int r = j >> 6;               // row within tile (64 float4 per row)
        long long n = n0 + r;
        float4 v = make_float4(0.f, 0.f, 0.f, 0.f);
        if (n < NN) v = xg[n * (DIN / 4) + (j & 63)];
        xsv[j] = v;
    }
    if (tid < MT) {
        long long n = n0 + tid;
        int g = -1;
        if (n < NN) {
            g = batch[n];
            if (g < 0 || g >= NG) g = -1;   // defensive: never index OOB
        }
        bid_s[tid] = g;
    }
    __syncthreads();

    // ---- GEMM phase: acc[m][c] = b1[c] + sum_k xs[row][k] * W1[k][c]
    const int tc = tid & 31;          // col group: cols 4*tc .. 4*tc+3
    const int tr = tid >> 5;          // row group: rows 8*tr .. 8*tr+7
    const int col0 = tc * 4;
    const int row0 = tr * 8;

    float4 b1v = *(const float4*)&b1[col0];
    float acc[8][4];
    #pragma unroll
    for (int m = 0; m < 8; ++m) {
        acc[m][0] = b1v.x; acc[m][1] = b1v.y; acc[m][2] = b1v.z; acc[m][3] = b1v.w;
    }

    for (int k0 = 0; k0 < DIN; k0 += 4) {
        float w[4][4];
        #pragma unroll
        for (int kk = 0; kk < 4; ++kk) {
            float4 wv = *(const float4*)&W1[(k0 + kk) * DATT + col0];
            w[kk][0] = wv.x; w[kk][1] = wv.y; w[kk][2] = wv.z; w[kk][3] = wv.w;
        }
        #pragma unroll
        for (int m = 0; m < 8; ++m) {
            float4 xv4 = *(const float4*)&xs[row0 + m][k0];
            float xv[4] = {xv4.x, xv4.y, xv4.z, xv4.w};
            #pragma unroll
            for (int kk = 0; kk < 4; ++kk)
                #pragma unroll
                for (int c = 0; c < 4; ++c)
                    acc[m][c] = fmaf(xv[kk], w[kk][c], acc[m][c]);
        }
    }

    // ---- attn = tanh(acc) @ W2 + b2, reduced over the 32 col-threads
    float4 w2v = *(const float4*)&W2[col0];
    float w2a[4] = {w2v.x, w2v.y, w2v.z, w2v.w};
    float b2s = b2[0];

    float p[8];
    #pragma unroll
    for (int m = 0; m < 8; ++m) {
        p[m] = tanhf(acc[m][0]) * w2a[0] + tanhf(acc[m][1]) * w2a[1]
             + tanhf(acc[m][2]) * w2a[2] + tanhf(acc[m][3]) * w2a[3];
    }
    #pragma unroll
    for (int m = 0; m < 8; ++m) {
        #pragma unroll
        for (int s = 16; s >= 1; s >>= 1)
            p[m] += __shfl_xor(p[m], s, 32);
        if (tc == 0) attn_s[row0 + m] = p[m] + b2s;
    }
    __syncthreads();

    // ---- pooling phase: thread = one dim d; serial over 64 nodes (sorted batch)
    float accum = 0.f;
    int gcur = bid_s[0];
    for (int n = 0; n < MT; ++n) {
        int g = bid_s[n];               // uniform across threads
        if (g != gcur) {
            if (gcur >= 0) atomicAdd(&out[(long long)gcur * DIN + tid], accum);
            accum = 0.f;
            gcur = g;
        }
        accum = fmaf(attn_s[n], xs[n][tid], accum);
    }
    if (gcur >= 0) atomicAdd(&out[(long long)gcur * DIN + tid], accum);
}

extern "C" void kernel_launch(void* const* d_in, const int* in_sizes, int n_in,
                              void* d_out, int out_size, void* d_ws, size_t ws_size,
                              hipStream_t stream) {
    const float* x     = (const float*)d_in[0];
    const int*   batch = (const int*)d_in[1];     // int32 (JAX x64 disabled)
    // d_in[2] = num_graphs scalar (hardcoded 4096)
    const float* W1 = (const float*)d_in[3];
    const float* b1 = (const float*)d_in[4];
    const float* W2 = (const float*)d_in[5];
    const float* b2 = (const float*)d_in[6];
    float* out = (float*)d_out;

    hipMemsetAsync(out, 0, (size_t)NG * DIN * sizeof(float), stream);

    int grid = (NN + MT - 1) / MT;    // 7813
    attnpool_kernel<<<grid, 256, 0, stream>>>(x, batch, W1, b1, W2, b2, out);
}

// Round 3
// 199.849 us; speedup vs baseline: 3.3406x; 3.3406x over previous
//
#include <hip/hip_runtime.h>
#include <hip/hip_bf16.h>

#define NN    500000
#define DIN   256
#define DATT  128
#define NG    4096
#define MT    64          // nodes per block tile

typedef __attribute__((ext_vector_type(8))) short short8;
typedef __attribute__((ext_vector_type(4))) float f32x4;

__device__ __forceinline__ unsigned short f2bf(float f) {
    unsigned int u = __float_as_uint(f);
    unsigned int r = (u + 0x7FFFu + ((u >> 16) & 1u)) >> 16;   // RNE
    return (unsigned short)r;
}

__device__ __forceinline__ float bf2f(unsigned short h) {
    return __uint_as_float((unsigned int)h << 16);
}

// tanh(x) = 1 - 2/(1+e^{2x}); stable for all x, monotone, |err| ~1e-6
__device__ __forceinline__ float tanh_fast(float v) {
    float e = __expf(2.f * v);
    return 1.f - 2.f * __builtin_amdgcn_rcpf(e + 1.f);
}

// one-time: W1 [256][128] fp32 -> W1t [128][256] bf16 (transposed) in d_ws
__global__ void prep_w1t(const float* __restrict__ W1, unsigned short* __restrict__ W1t) {
    int c = blockIdx.x;      // 0..127 (DATT)
    int k = threadIdx.x;     // 0..255 (DIN)
    W1t[c * DIN + k] = f2bf(W1[k * DATT + c]);
}

// Fused: h = tanh(x@W1+b1); attn = h@W2+b2; out[batch[n]] += attn[n]*x[n]
// 256 threads = 4 waves. xs: bf16 [64][256] XOR-swizzled (byte ^= (row&7)<<4).
// Wave w computes h rows 0..63 x cols [32w,32w+32) via mfma_f32_16x16x32_bf16.
// Cross-wave attn reduction through part[4][64]; pooling with sorted-batch
// register accumulation + boundary atomics.
__global__ __launch_bounds__(256, 3)
void attnpool_kernel(const float* __restrict__ x,
                     const int* __restrict__ batch,
                     const unsigned short* __restrict__ W1t,
                     const float* __restrict__ b1,
                     const float* __restrict__ W2,
                     const float* __restrict__ b2,
                     float* __restrict__ out)
{
    __shared__ unsigned short xs[MT * DIN];   // 32 KB, swizzled
    __shared__ float part[4][MT];
    __shared__ float attn_s[MT];
    __shared__ int   bid_s[MT];

    const int tid = threadIdx.x;
    const int w   = tid >> 6;        // wave 0..3
    const int l   = tid & 63;        // lane
    const int lr  = l & 15;
    const int lg  = l >> 4;
    const long long n0 = (long long)blockIdx.x * MT;

    // ---- stage x tile: fp32 global -> bf16 swizzled LDS (reg-staged)
    const float4* xg = (const float4*)x;
    #pragma unroll
    for (int i = 0; i < 16; ++i) {
        int j  = tid + i * 256;       // float4-chunk id, 0..4095
        int r  = j >> 6;              // row in tile
        int c4 = j & 63;              // float4 index within row
        long long n = n0 + r;
        float4 v = make_float4(0.f, 0.f, 0.f, 0.f);
        if (n < NN) v = xg[n * 64 + c4];
        unsigned int w0 = (unsigned int)f2bf(v.x) | ((unsigned int)f2bf(v.y) << 16);
        unsigned int w1 = (unsigned int)f2bf(v.z) | ((unsigned int)f2bf(v.w) << 16);
        int byte = r * 512 + ((c4 * 8) ^ ((r & 7) << 4));
        *reinterpret_cast<uint2*>(reinterpret_cast<char*>(xs) + byte) = make_uint2(w0, w1);
    }
    if (tid < MT) {
        long long n = n0 + tid;
        int g = -1;
        if (n < NN) {
            g = batch[n];
            if (g < 0 || g >= NG) g = -1;
        }
        bid_s[tid] = g;
    }

    // ---- B fragments: W1t bf16, L2-resident. wave w -> cols [32w, 32w+32)
    // b[nt][kc] elem i = B[k=32kc+8lg+i][col=32w+16nt+lr] = W1t[col][32kc+8lg+i]
    short8 bfr[2][8];
    #pragma unroll
    for (int nt = 0; nt < 2; ++nt) {
        int col = 32 * w + 16 * nt + lr;
        #pragma unroll
        for (int kc = 0; kc < 8; ++kc)
            bfr[nt][kc] = *reinterpret_cast<const short8*>(&W1t[col * DIN + 32 * kc + 8 * lg]);
    }

    __syncthreads();

    // ---- MFMA: acc[mt][nt] covers rows [16mt,16mt+16) x cols [32w+16nt, +16)
    f32x4 acc[4][2];
    #pragma unroll
    for (int mt = 0; mt < 4; ++mt)
        #pragma unroll
        for (int nt = 0; nt < 2; ++nt)
            acc[mt][nt] = (f32x4){0.f, 0.f, 0.f, 0.f};

    #pragma unroll
    for (int mt = 0; mt < 4; ++mt) {
        short8 afr[8];
        int row = 16 * mt + lr;
        #pragma unroll
        for (int kc = 0; kc < 8; ++kc) {
            int byte = row * 512 + (((32 * kc + 8 * lg) * 2) ^ ((row & 7) << 4));
            afr[kc] = *reinterpret_cast<const short8*>(reinterpret_cast<const char*>(xs) + byte);
        }
        #pragma unroll
        for (int nt = 0; nt < 2; ++nt)
            #pragma unroll
            for (int kc = 0; kc < 8; ++kc)
                acc[mt][nt] = __builtin_amdgcn_mfma_f32_16x16x32_bf16(afr[kc], bfr[nt][kc], acc[mt][nt], 0, 0, 0);
    }

    // ---- attn partials: row = 16mt + 4*lg + j ; lane's cols = 32w+16nt+lr
    float b1v[2], w2v[2];
    #pragma unroll
    for (int nt = 0; nt < 2; ++nt) {
        b1v[nt] = b1[32 * w + 16 * nt + lr];
        w2v[nt] = W2[32 * w + 16 * nt + lr];
    }
    #pragma unroll
    for (int mt = 0; mt < 4; ++mt)
        #pragma unroll
        for (int j = 0; j < 4; ++j) {
            float s = tanh_fast(acc[mt][0][j] + b1v[0]) * w2v[0]
                    + tanh_fast(acc[mt][1][j] + b1v[1]) * w2v[1];
            s += __shfl_xor(s, 1);
            s += __shfl_xor(s, 2);
            s += __shfl_xor(s, 4);
            s += __shfl_xor(s, 8);
            if (lr == 0) part[w][16 * mt + 4 * lg + j] = s;
        }
    __syncthreads();

    if (tid < MT)
        attn_s[tid] = b2[0] + part[0][tid] + part[1][tid] + part[2][tid] + part[3][tid];
    __syncthreads();

    // ---- pooling: thread = dim d; serial over 64 sorted nodes
    const int d = tid;
    float accum = 0.f;
    int gcur = bid_s[0];
    for (int n = 0; n < MT; ++n) {
        int g = bid_s[n];               // uniform across threads
        if (g != gcur) {
            if (gcur >= 0) atomicAdd(&out[(long long)gcur * DIN + d], accum);
            accum = 0.f;
            gcur = g;
        }
        int byte = n * 512 + ((d * 2) ^ ((n & 7) << 4));
        float xv = bf2f(*reinterpret_cast<const unsigned short*>(reinterpret_cast<const char*>(xs) + byte));
        accum = fmaf(attn_s[n], xv, accum);
    }
    if (gcur >= 0) atomicAdd(&out[(long long)gcur * DIN + d], accum);
}

extern "C" void kernel_launch(void* const* d_in, const int* in_sizes, int n_in,
                              void* d_out, int out_size, void* d_ws, size_t ws_size,
                              hipStream_t stream) {
    const float* x     = (const float*)d_in[0];
    const int*   batch = (const int*)d_in[1];     // int32 (JAX x64 disabled)
    // d_in[2] = num_graphs scalar (hardcoded 4096)
    const float* W1 = (const float*)d_in[3];
    const float* b1 = (const float*)d_in[4];
    const float* W2 = (const float*)d_in[5];
    const float* b2 = (const float*)d_in[6];
    float* out = (float*)d_out;
    unsigned short* W1t = (unsigned short*)d_ws;   // 64 KB

    hipMemsetAsync(out, 0, (size_t)NG * DIN * sizeof(float), stream);
    prep_w1t<<<DATT, DIN, 0, stream>>>(W1, W1t);

    int grid = (NN + MT - 1) / MT;    // 7813
    attnpool_kernel<<<grid, 256, 0, stream>>>(x, batch, W1t, b1, W2, b2, out);
}